// Round 11
// baseline (319.068 us; speedup 1.0000x reference)
//
#include <hip/hip_runtime.h>

// CAttention on MI355X (gfx950). Inputs f32, output f32.
// Q = box3(x)*log2(e), K = V = normalize(x+EPS), softmax over keys, per batch.
// Round 11: occupancy x2 — sP aliases sK (3rd barrier), LDS 36864 B -> 4 blocks/CU;
// S=8 -> 1024 blocks -> 16 waves/CU; bf16 opart via single-pass 256B-chunk epilogue.
// Keeps R10's verified staging (sK/sV LDS, reg prefetch) + S^T trick.
// ws: kmat bf16 @0 | kT bf16 @4M | xbT bf16 @8M | lsum f32 @12M | inv f32 @12.5M | opart bf16 @13M.

typedef short bf16x8 __attribute__((ext_vector_type(8)));
typedef float f32x4 __attribute__((ext_vector_type(4)));
typedef unsigned short u16x4 __attribute__((ext_vector_type(4)));
typedef unsigned int u32x2 __attribute__((ext_vector_type(2)));

#define L2E 1.4426950408889634f

__device__ __forceinline__ unsigned short f2bf(float f) {
    unsigned int u;
    __builtin_memcpy(&u, &f, 4);
    u = u + 0x7FFFu + ((u >> 16) & 1u);   // RNE
    return (unsigned short)(u >> 16);
}
__device__ __forceinline__ float bf2f(unsigned short h) {
    unsigned int u = ((unsigned int)h) << 16;
    float f;
    __builtin_memcpy(&f, &u, 4);
    return f;
}
// pack two f32 -> bf16 pair (round to nearest, ties up)
__device__ __forceinline__ unsigned int pk_bf16(float a, float b) {
    unsigned int ua, ub;
    __builtin_memcpy(&ua, &a, 4);
    __builtin_memcpy(&ub, &b, 4);
    return ((ua + 0x8000u) >> 16) | ((ub + 0x8000u) & 0xFFFF0000u);
}

// ---------------- K0: inv[b][l] = rsqrt(sum_c (x+eps)^2) — fully coalesced ---------------
__global__ void prep_inv(const float* __restrict__ x, float* __restrict__ inv) {
    const int b = blockIdx.y, l = blockIdx.x * 256 + threadIdx.x;
    const float* xb = x + (size_t)b * 128 * 4096 + l;
    float sq = 0.f;
#pragma unroll 16
    for (int c = 0; c < 128; c++) {
        float v = xb[(size_t)c * 4096] + 1e-7f;
        sq += v * v;
    }
    inv[b * 4096 + l] = rsqrtf(sq);
}

// ---------------- K1: prep_main: kmat, kT, xbT for one (p-row, b, c-half) ----------------
__global__ void prep_main(const float* __restrict__ x,
                          const float* __restrict__ inv,
                          unsigned short* __restrict__ kmat,
                          unsigned short* __restrict__ kT,
                          unsigned short* __restrict__ xbT) {
    const int p = blockIdx.x, b = blockIdx.y, cb = blockIdx.z * 64;
    const int t = threadIdx.x, wave = t >> 6, lane = t & 63;

    __shared__ float sX[8][3][66];
    __shared__ float sMidT[64 * 68];
    __shared__ __align__(16) unsigned short sQ[64 * 80];
    __shared__ float sInv[64];
    if (t < 64) sInv[t] = inv[b * 4096 + p * 64 + t];

    for (int c0 = 0; c0 < 64; c0 += 8) {
        __syncthreads();
#pragma unroll
        for (int i = 0; i < 6; i++) {
            int pair = wave * 6 + i;
            int cc = pair / 3, r = pair - cc * 3;
            int pp = p + r - 1;
            float v = 0.f;
            if ((unsigned)pp < 64u)
                v = x[((size_t)b * 128 + cb + c0 + cc) * 4096 + pp * 64 + lane];
            sX[cc][r][1 + lane] = v;
        }
        if (t < 48) {
            int cc = t / 6, rr = (t % 6) >> 1, side = t & 1;
            sX[cc][rr][side * 65] = 0.f;
        }
        __syncthreads();
#pragma unroll
        for (int j = 0; j < 2; j++) {
            int cc = wave * 2 + j;
            float mid = sX[cc][1][1 + lane] + 1e-7f;
            sMidT[lane * 68 + c0 + cc] = mid;
            float sbox = 0.f;
#pragma unroll
            for (int r = 0; r < 3; r++)
                sbox += sX[cc][r][lane] + sX[cc][r][lane + 1] + sX[cc][r][lane + 2];
            sQ[lane * 80 + c0 + cc] = f2bf(sbox * L2E);
        }
    }
    __syncthreads();

#pragma unroll
    for (int i = 0; i < 2; i++) {
        int u = i * 256 + t, row = u >> 3, g = u & 7;
        *(bf16x8*)(xbT + ((size_t)b * 4096 + p * 64 + row) * 128 + cb + g * 8) =
            *(const bf16x8*)(sQ + row * 80 + g * 8);
    }
#pragma unroll
    for (int i = 0; i < 2; i++) {
        int u = i * 256 + t, q = u >> 3, g = u & 7;
        float iv = sInv[q];
        f32x4 a = *(const f32x4*)(sMidT + q * 68 + g * 8);
        f32x4 c = *(const f32x4*)(sMidT + q * 68 + g * 8 + 4);
        unsigned int w[4];
        w[0] = pk_bf16(a[0] * iv, a[1] * iv);
        w[1] = pk_bf16(a[2] * iv, a[3] * iv);
        w[2] = pk_bf16(c[0] * iv, c[1] * iv);
        w[3] = pk_bf16(c[2] * iv, c[3] * iv);
        *(uint4*)(kmat + ((size_t)b * 4096 + p * 64 + q) * 128 + cb + g * 8) =
            make_uint4(w[0], w[1], w[2], w[3]);
    }
    {
        int c = t >> 2, qg = t & 3;
        unsigned int w[8];
#pragma unroll
        for (int j = 0; j < 8; j++) {
            int ql = qg * 16 + j * 2;
            w[j] = pk_bf16(sMidT[ql * 68 + c] * sInv[ql],
                           sMidT[(ql + 1) * 68 + c] * sInv[ql + 1]);
        }
        unsigned short* dst = kT + ((size_t)b * 128 + cb + c) * 4096 + p * 64 + qg * 16;
        *(uint4*)(dst) = make_uint4(w[0], w[1], w[2], w[3]);
        *(uint4*)(dst + 8) = make_uint4(w[4], w[5], w[6], w[7]);
    }
}

// ---------------- K2: split-K flash (sP aliases sK; 4 blocks/CU) -------------------------
#define SK_STRIDE 136
#define SV_STRIDE 72
#define SP_STRIDE 72
#define SK_REGION 9216                 // padded: sK uses 8704, sP (4*32*72=9216) aliases it
#define SV_ELEMS (128 * SV_STRIDE)     // 9216
#define SMEM_ELEMS (SK_REGION + SV_ELEMS)  // 18432 u16 = 36864 B -> 4 blocks/CU

__global__ void __launch_bounds__(256, 4) flash_attn(
        const unsigned short* __restrict__ kmat,
        const unsigned short* __restrict__ kT,
        const unsigned short* __restrict__ xbT,
        unsigned short* __restrict__ opart,
        float* __restrict__ lsum,
        int nsplit, int qbshift) {
    const int combo = blockIdx.x & (4 * nsplit - 1);
    const int qb = blockIdx.x >> qbshift;        // 128-query tile, 0..31
    const int b = combo & 3, split = combo >> 2;
    const int nk = 4096 / nsplit, NIT = nk >> 6, kt_base = split * nk;
    const int t = threadIdx.x;
    const int wave = t >> 6, lane = t & 63;
    const int l16 = lane & 15, quad = lane >> 4;

    __shared__ __align__(16) unsigned short smem[SMEM_ELEMS];
    unsigned short* sK = smem;                              // [64 keys][136] in [0, 9216)
    unsigned short* sV = smem + SK_REGION;                  // [128 ch][72]
    unsigned short* sP = smem + wave * 32 * SP_STRIDE;      // aliases sK region (dead after QK)

    // Q frags (B-operand of S^T): B[n=q=l16][k=c=quad*8+j]
    bf16x8 aq[2][4];
#pragma unroll
    for (int h = 0; h < 2; h++) {
        const unsigned short* xq =
            xbT + ((size_t)b * 4096 + qb * 128 + wave * 32 + h * 16 + l16) * 128 + quad * 8;
#pragma unroll
        for (int cc = 0; cc < 4; cc++) aq[h][cc] = *(const bf16x8*)(xq + cc * 32);
    }

    f32x4 o[2][8];
#pragma unroll
    for (int h = 0; h < 2; h++)
#pragma unroll
        for (int n = 0; n < 8; n++) o[h][n] = (f32x4){0.f, 0.f, 0.f, 0.f};
    float rs[2] = {0.f, 0.f};

    const unsigned short* kmb = kmat + (size_t)b * 4096 * 128;
    const unsigned short* ktb = kT + (size_t)b * 128 * 4096;

    bf16x8 kreg[4], vreg[4];
#pragma unroll
    for (int i = 0; i < 4; i++) {
        int e = i * 2048 + t * 8;
        kreg[i] = *(const bf16x8*)(kmb + (size_t)(kt_base + (e >> 7)) * 128 + (e & 127));
        vreg[i] = *(const bf16x8*)(ktb + (size_t)(e >> 6) * 4096 + kt_base + (e & 63));
    }

    for (int it = 0; it < NIT; it++) {
        __syncthreads();                          // (A) prior iter's sP/sV reads done
#pragma unroll
        for (int i = 0; i < 4; i++) {
            int e = i * 2048 + t * 8;
            *(bf16x8*)(sK + (e >> 7) * SK_STRIDE + (e & 127)) = kreg[i];
            *(bf16x8*)(sV + (e >> 6) * SV_STRIDE + (e & 63)) = vreg[i];
        }
        __syncthreads();                          // (B) tiles visible
        if (it + 1 < NIT) {
            int kt0 = kt_base + (it + 1) * 64;
#pragma unroll
            for (int i = 0; i < 4; i++) {
                int e = i * 2048 + t * 8;
                kreg[i] = *(const bf16x8*)(kmb + (size_t)(kt0 + (e >> 7)) * 128 + (e & 127));
                vreg[i] = *(const bf16x8*)(ktb + (size_t)(e >> 6) * 4096 + kt0 + (e & 63));
            }
        }

        // S^T = K Q^T: D: lane holds S^T[key = k4*16 + quad*4 + r][q = l16]
        f32x4 s[2][4];
#pragma unroll
        for (int h = 0; h < 2; h++)
#pragma unroll
            for (int k4 = 0; k4 < 4; k4++) s[h][k4] = (f32x4){0.f, 0.f, 0.f, 0.f};
#pragma unroll
        for (int cc = 0; cc < 4; cc++) {
#pragma unroll
            for (int k4 = 0; k4 < 4; k4++) {
                bf16x8 ak = *(const bf16x8*)(sK + (k4 * 16 + l16) * SK_STRIDE + cc * 32 + quad * 8);
                s[0][k4] = __builtin_amdgcn_mfma_f32_16x16x32_bf16(ak, aq[0][cc], s[0][k4], 0, 0, 0);
                s[1][k4] = __builtin_amdgcn_mfma_f32_16x16x32_bf16(ak, aq[1][cc], s[1][k4], 0, 0, 0);
            }
        }
        __syncthreads();                          // (C) all QK reads done -> sP alias safe

        // p = 2^s; lane-local row-sum; b64-pack consecutive keys -> sP
#pragma unroll
        for (int h = 0; h < 2; h++) {
#pragma unroll
            for (int k4 = 0; k4 < 4; k4++) {
                float p0 = exp2f(s[h][k4][0]), p1 = exp2f(s[h][k4][1]);
                float p2 = exp2f(s[h][k4][2]), p3 = exp2f(s[h][k4][3]);
                rs[h] += (p0 + p1) + (p2 + p3);
                u32x2 d;
                d[0] = pk_bf16(p0, p1);
                d[1] = pk_bf16(p2, p3);
                *(u32x2*)(sP + (h * 16 + l16) * SP_STRIDE + k4 * 16 + quad * 4) = d;
            }
        }
        asm volatile("" ::: "memory");
        bf16x8 pa[2][2];
#pragma unroll
        for (int h = 0; h < 2; h++)
#pragma unroll
            for (int kc = 0; kc < 2; kc++)
                pa[h][kc] = *(const bf16x8*)(sP + (h * 16 + l16) * SP_STRIDE + kc * 32 + quad * 8);
        asm volatile("" ::: "memory");

        // O += P V
#pragma unroll
        for (int kc = 0; kc < 2; kc++)
#pragma unroll
            for (int n = 0; n < 8; n++) {
                bf16x8 bv = *(const bf16x8*)(sV + (n * 16 + l16) * SV_STRIDE + kc * 32 + quad * 8);
                o[0][n] = __builtin_amdgcn_mfma_f32_16x16x32_bf16(pa[0][kc], bv, o[0][n], 0, 0, 0);
                o[1][n] = __builtin_amdgcn_mfma_f32_16x16x32_bf16(pa[1][kc], bv, o[1][n], 0, 0, 0);
            }
    }

    // row-sums reduce across quads; store lsum
#pragma unroll
    for (int h = 0; h < 2; h++) {
        rs[h] += __shfl_xor(rs[h], 16);
        rs[h] += __shfl_xor(rs[h], 32);
    }
    if (lane < 16) {
#pragma unroll
        for (int h = 0; h < 2; h++)
            lsum[(size_t)(split * 4 + b) * 4096 + qb * 128 + wave * 32 + h * 16 + lane] = rs[h];
    }

    // single-pass bf16 epilogue: sO [128 c][144] u16 = 36864 B (aliases all smem)
    __syncthreads();
    unsigned short* sO = smem;
    unsigned int* sO32 = (unsigned int*)smem;
#pragma unroll
    for (int h = 0; h < 2; h++)
#pragma unroll
        for (int n = 0; n < 8; n++) {
            int c = n * 16 + l16;
            int q = wave * 32 + h * 16 + quad * 4;     // even, so >>1 below is exact
            sO32[(c * 144 + q) >> 1] = pk_bf16(o[h][n][0], o[h][n][1]);
            sO32[(c * 144 + q + 2) >> 1] = pk_bf16(o[h][n][2], o[h][n][3]);
        }
    __syncthreads();
#pragma unroll
    for (int i = 0; i < 8; i++) {
        int u = i * 256 + t, c = u >> 4, chunk = u & 15;   // 128 c rows x 16 chunks of 16B
        *(uint4*)(opart + ((size_t)(split * 4 + b) * 128 + c) * 4096 + qb * 128 + chunk * 8) =
            *(const uint4*)(sO + c * 144 + chunk * 8);
    }
}

// ---------------- K3: combine splits + mask blend (bf16 opart) ---------------------------
// grid (64 qb64, 4 b) x 256.
__global__ void combine(const unsigned short* __restrict__ opart,
                        const float* __restrict__ lsum,
                        const float* __restrict__ x,
                        const float* __restrict__ mask,
                        float* __restrict__ out, int S) {
    const int qb = blockIdx.x, b = blockIdx.y, t = threadIdx.x;
    __shared__ float Linv[64];
    if (t < 64) {
        float L = 0.f;
        for (int s2 = 0; s2 < S; s2++)
            L += lsum[(size_t)(s2 * 4 + b) * 4096 + qb * 64 + t];
        Linv[t] = 1.f / fmaxf(L, 1e-37f);
    }
    __syncthreads();
#pragma unroll
    for (int i = 0; i < 8; i++) {
        int c = (t >> 4) + i * 16, qj = (t & 15) * 4;
        size_t qoff = (size_t)qb * 64 + qj;
        f32x4 acc = (f32x4){0.f, 0.f, 0.f, 0.f};
        for (int s2 = 0; s2 < S; s2++) {
            u16x4 pv = *(const u16x4*)(opart + ((size_t)(s2 * 4 + b) * 128 + c) * 4096 + qoff);
#pragma unroll
            for (int j = 0; j < 4; j++) acc[j] += bf2f(pv[j]);
        }
        f32x4 xv = *(const f32x4*)(x + ((size_t)b * 128 + c) * 4096 + qoff);
        f32x4 mv = *(const f32x4*)(mask + (size_t)b * 4096 + qoff);
        f32x4 res;
#pragma unroll
        for (int j = 0; j < 4; j++)
            res[j] = acc[j] * Linv[qj + j] * (1.f - mv[j]) * (1.f / 9.f) + xv[j] * mv[j];
        *(f32x4*)(out + ((size_t)b * 128 + c) * 4096 + qoff) = res;
    }
}

extern "C" void kernel_launch(void* const* d_in, const int* in_sizes, int n_in,
                              void* d_out, int out_size, void* d_ws, size_t ws_size,
                              hipStream_t stream) {
    const float* x = (const float*)d_in[0];     // f32 (4,128,64,64)
    const float* mask = (const float*)d_in[1];  // f32 (4,1,64,64)
    float* out = (float*)d_out;                 // f32 (4,128,64,64)
    char* ws = (char*)d_ws;
    unsigned short* kmat = (unsigned short*)(ws);
    unsigned short* kT   = (unsigned short*)(ws + (size_t)4 * 1024 * 1024);
    unsigned short* xbT  = (unsigned short*)(ws + (size_t)8 * 1024 * 1024);
    float* lsum          = (float*)(ws + (size_t)12 * 1024 * 1024);           // <= 512 KiB
    float* inv           = (float*)(ws + (size_t)12 * 1024 * 1024 + 512 * 1024);
    unsigned short* opart = (unsigned short*)(ws + (size_t)13 * 1024 * 1024); // S*4 MiB bf16

    // ws need: 13 MiB + S*4 MiB
    int S, qbshift;
    if (ws_size >= (size_t)45 * 1024 * 1024)      { S = 8; qbshift = 5; }
    else if (ws_size >= (size_t)29 * 1024 * 1024) { S = 4; qbshift = 4; }
    else if (ws_size >= (size_t)21 * 1024 * 1024) { S = 2; qbshift = 3; }
    else return;

    prep_inv<<<dim3(16, 4), 256, 0, stream>>>(x, inv);
    prep_main<<<dim3(64, 4, 2), 256, 0, stream>>>(x, inv, kmat, kT, xbT);
    flash_attn<<<dim3(32 * 4 * S), 256, 0, stream>>>(kmat, kT, xbT, opart, lsum, S, qbshift);
    combine<<<dim3(64, 4), 256, 0, stream>>>(opart, lsum, x, mask, out, S);
}

// Round 12
// 257.532 us; speedup vs baseline: 1.2389x; 1.2389x over previous
//
#include <hip/hip_runtime.h>

// CAttention on MI355X (gfx950). Inputs f32, output f32.
// Q = box3(x)*log2(e), K = V = normalize(x+EPS), softmax over keys, per batch.
// Round 12: R11 structure, but launch_bounds(256,3) — R11's (256,4) forced VGPR 124->64
// and spilled staging regs to scratch (FETCH 416MB/WRITE 543MB = ~1GB spill traffic).
// LDS 36864B and VGPR~124 both permit 4 blocks/CU naturally. prep_inv now 256 blocks.
// ws: kmat bf16 @0 | kT bf16 @4M | xbT bf16 @8M | lsum f32 @12M | inv f32 @12.5M | opart bf16 @13M.

typedef short bf16x8 __attribute__((ext_vector_type(8)));
typedef float f32x4 __attribute__((ext_vector_type(4)));
typedef unsigned short u16x4 __attribute__((ext_vector_type(4)));
typedef unsigned int u32x2 __attribute__((ext_vector_type(2)));

#define L2E 1.4426950408889634f

__device__ __forceinline__ unsigned short f2bf(float f) {
    unsigned int u;
    __builtin_memcpy(&u, &f, 4);
    u = u + 0x7FFFu + ((u >> 16) & 1u);   // RNE
    return (unsigned short)(u >> 16);
}
__device__ __forceinline__ float bf2f(unsigned short h) {
    unsigned int u = ((unsigned int)h) << 16;
    float f;
    __builtin_memcpy(&f, &u, 4);
    return f;
}
// pack two f32 -> bf16 pair (round to nearest, ties up)
__device__ __forceinline__ unsigned int pk_bf16(float a, float b) {
    unsigned int ua, ub;
    __builtin_memcpy(&ua, &a, 4);
    __builtin_memcpy(&ub, &b, 4);
    return ((ua + 0x8000u) >> 16) | ((ub + 0x8000u) & 0xFFFF0000u);
}

// ---------------- K0: inv[b][l] = rsqrt(sum_c (x+eps)^2) ---------------------------------
// grid (64, 4) x 256: block covers 64 l; wave w sums c in [w*32, w*32+32).
__global__ void prep_inv(const float* __restrict__ x, float* __restrict__ inv) {
    const int b = blockIdx.y, l0 = blockIdx.x * 64, t = threadIdx.x;
    const int wave = t >> 6, lane = t & 63;
    const float* xb = x + (size_t)b * 128 * 4096 + l0 + lane;
    float sq = 0.f;
#pragma unroll
    for (int i = 0; i < 32; i++) {
        float v = xb[(size_t)(wave * 32 + i) * 4096] + 1e-7f;
        sq += v * v;
    }
    __shared__ float sqp[256];
    sqp[t] = sq;
    __syncthreads();
    if (t < 64)
        inv[b * 4096 + l0 + t] = rsqrtf(sqp[t] + sqp[64 + t] + sqp[128 + t] + sqp[192 + t]);
}

// ---------------- K1: prep_main: kmat, kT, xbT for one (p-row, b, c-half) ----------------
__global__ void prep_main(const float* __restrict__ x,
                          const float* __restrict__ inv,
                          unsigned short* __restrict__ kmat,
                          unsigned short* __restrict__ kT,
                          unsigned short* __restrict__ xbT) {
    const int p = blockIdx.x, b = blockIdx.y, cb = blockIdx.z * 64;
    const int t = threadIdx.x, wave = t >> 6, lane = t & 63;

    __shared__ float sX[8][3][66];
    __shared__ float sMidT[64 * 68];
    __shared__ __align__(16) unsigned short sQ[64 * 80];
    __shared__ float sInv[64];
    if (t < 64) sInv[t] = inv[b * 4096 + p * 64 + t];

    for (int c0 = 0; c0 < 64; c0 += 8) {
        __syncthreads();
#pragma unroll
        for (int i = 0; i < 6; i++) {
            int pair = wave * 6 + i;
            int cc = pair / 3, r = pair - cc * 3;
            int pp = p + r - 1;
            float v = 0.f;
            if ((unsigned)pp < 64u)
                v = x[((size_t)b * 128 + cb + c0 + cc) * 4096 + pp * 64 + lane];
            sX[cc][r][1 + lane] = v;
        }
        if (t < 48) {
            int cc = t / 6, rr = (t % 6) >> 1, side = t & 1;
            sX[cc][rr][side * 65] = 0.f;
        }
        __syncthreads();
#pragma unroll
        for (int j = 0; j < 2; j++) {
            int cc = wave * 2 + j;
            float mid = sX[cc][1][1 + lane] + 1e-7f;
            sMidT[lane * 68 + c0 + cc] = mid;
            float sbox = 0.f;
#pragma unroll
            for (int r = 0; r < 3; r++)
                sbox += sX[cc][r][lane] + sX[cc][r][lane + 1] + sX[cc][r][lane + 2];
            sQ[lane * 80 + c0 + cc] = f2bf(sbox * L2E);
        }
    }
    __syncthreads();

#pragma unroll
    for (int i = 0; i < 2; i++) {
        int u = i * 256 + t, row = u >> 3, g = u & 7;
        *(bf16x8*)(xbT + ((size_t)b * 4096 + p * 64 + row) * 128 + cb + g * 8) =
            *(const bf16x8*)(sQ + row * 80 + g * 8);
    }
#pragma unroll
    for (int i = 0; i < 2; i++) {
        int u = i * 256 + t, q = u >> 3, g = u & 7;
        float iv = sInv[q];
        f32x4 a = *(const f32x4*)(sMidT + q * 68 + g * 8);
        f32x4 c = *(const f32x4*)(sMidT + q * 68 + g * 8 + 4);
        unsigned int w[4];
        w[0] = pk_bf16(a[0] * iv, a[1] * iv);
        w[1] = pk_bf16(a[2] * iv, a[3] * iv);
        w[2] = pk_bf16(c[0] * iv, c[1] * iv);
        w[3] = pk_bf16(c[2] * iv, c[3] * iv);
        *(uint4*)(kmat + ((size_t)b * 4096 + p * 64 + q) * 128 + cb + g * 8) =
            make_uint4(w[0], w[1], w[2], w[3]);
    }
    {
        int c = t >> 2, qg = t & 3;
        unsigned int w[8];
#pragma unroll
        for (int j = 0; j < 8; j++) {
            int ql = qg * 16 + j * 2;
            w[j] = pk_bf16(sMidT[ql * 68 + c] * sInv[ql],
                           sMidT[(ql + 1) * 68 + c] * sInv[ql + 1]);
        }
        unsigned short* dst = kT + ((size_t)b * 128 + cb + c) * 4096 + p * 64 + qg * 16;
        *(uint4*)(dst) = make_uint4(w[0], w[1], w[2], w[3]);
        *(uint4*)(dst + 8) = make_uint4(w[4], w[5], w[6], w[7]);
    }
}

// ---------------- K2: split-K flash (sP aliases sK; no reg spill) ------------------------
#define SK_STRIDE 136
#define SV_STRIDE 72
#define SP_STRIDE 72
#define SK_REGION 9216                 // sK uses 8704; sP (4*32*72=9216) aliases this region
#define SV_ELEMS (128 * SV_STRIDE)     // 9216
#define SMEM_ELEMS (SK_REGION + SV_ELEMS)  // 18432 u16 = 36864 B -> LDS allows 4 blocks/CU

__global__ void __launch_bounds__(256, 3) flash_attn(
        const unsigned short* __restrict__ kmat,
        const unsigned short* __restrict__ kT,
        const unsigned short* __restrict__ xbT,
        unsigned short* __restrict__ opart,
        float* __restrict__ lsum,
        int nsplit, int qbshift) {
    const int combo = blockIdx.x & (4 * nsplit - 1);
    const int qb = blockIdx.x >> qbshift;        // 128-query tile, 0..31
    const int b = combo & 3, split = combo >> 2;
    const int nk = 4096 / nsplit, NIT = nk >> 6, kt_base = split * nk;
    const int t = threadIdx.x;
    const int wave = t >> 6, lane = t & 63;
    const int l16 = lane & 15, quad = lane >> 4;

    __shared__ __align__(16) unsigned short smem[SMEM_ELEMS];
    unsigned short* sK = smem;                              // [64 keys][136] in [0, 9216)
    unsigned short* sV = smem + SK_REGION;                  // [128 ch][72]
    unsigned short* sP = smem + wave * 32 * SP_STRIDE;      // aliases sK (dead after QK^T)

    // Q frags (B-operand of S^T): B[n=q=l16][k=c=quad*8+j]
    bf16x8 aq[2][4];
#pragma unroll
    for (int h = 0; h < 2; h++) {
        const unsigned short* xq =
            xbT + ((size_t)b * 4096 + qb * 128 + wave * 32 + h * 16 + l16) * 128 + quad * 8;
#pragma unroll
        for (int cc = 0; cc < 4; cc++) aq[h][cc] = *(const bf16x8*)(xq + cc * 32);
    }

    f32x4 o[2][8];
#pragma unroll
    for (int h = 0; h < 2; h++)
#pragma unroll
        for (int n = 0; n < 8; n++) o[h][n] = (f32x4){0.f, 0.f, 0.f, 0.f};
    float rs[2] = {0.f, 0.f};

    const unsigned short* kmb = kmat + (size_t)b * 4096 * 128;
    const unsigned short* ktb = kT + (size_t)b * 128 * 4096;

    bf16x8 kreg[4], vreg[4];
#pragma unroll
    for (int i = 0; i < 4; i++) {
        int e = i * 2048 + t * 8;
        kreg[i] = *(const bf16x8*)(kmb + (size_t)(kt_base + (e >> 7)) * 128 + (e & 127));
        vreg[i] = *(const bf16x8*)(ktb + (size_t)(e >> 6) * 4096 + kt_base + (e & 63));
    }

    for (int it = 0; it < NIT; it++) {
        __syncthreads();                          // (A) prior iter's sP/sV reads done
#pragma unroll
        for (int i = 0; i < 4; i++) {
            int e = i * 2048 + t * 8;
            *(bf16x8*)(sK + (e >> 7) * SK_STRIDE + (e & 127)) = kreg[i];
            *(bf16x8*)(sV + (e >> 6) * SV_STRIDE + (e & 63)) = vreg[i];
        }
        __syncthreads();                          // (B) tiles visible
        if (it + 1 < NIT) {
            int kt0 = kt_base + (it + 1) * 64;
#pragma unroll
            for (int i = 0; i < 4; i++) {
                int e = i * 2048 + t * 8;
                kreg[i] = *(const bf16x8*)(kmb + (size_t)(kt0 + (e >> 7)) * 128 + (e & 127));
                vreg[i] = *(const bf16x8*)(ktb + (size_t)(e >> 6) * 4096 + kt0 + (e & 63));
            }
        }

        // S^T = K Q^T: lane holds S^T[key = k4*16 + quad*4 + r][q = l16]
        f32x4 s[2][4];
#pragma unroll
        for (int h = 0; h < 2; h++)
#pragma unroll
            for (int k4 = 0; k4 < 4; k4++) s[h][k4] = (f32x4){0.f, 0.f, 0.f, 0.f};
#pragma unroll
        for (int cc = 0; cc < 4; cc++) {
#pragma unroll
            for (int k4 = 0; k4 < 4; k4++) {
                bf16x8 ak = *(const bf16x8*)(sK + (k4 * 16 + l16) * SK_STRIDE + cc * 32 + quad * 8);
                s[0][k4] = __builtin_amdgcn_mfma_f32_16x16x32_bf16(ak, aq[0][cc], s[0][k4], 0, 0, 0);
                s[1][k4] = __builtin_amdgcn_mfma_f32_16x16x32_bf16(ak, aq[1][cc], s[1][k4], 0, 0, 0);
            }
        }
        __syncthreads();                          // (C) QK reads done -> sP alias safe

        // p = 2^s; lane-local row-sum; b64-pack consecutive keys -> sP
#pragma unroll
        for (int h = 0; h < 2; h++) {
#pragma unroll
            for (int k4 = 0; k4 < 4; k4++) {
                float p0 = exp2f(s[h][k4][0]), p1 = exp2f(s[h][k4][1]);
                float p2 = exp2f(s[h][k4][2]), p3 = exp2f(s[h][k4][3]);
                rs[h] += (p0 + p1) + (p2 + p3);
                u32x2 d;
                d[0] = pk_bf16(p0, p1);
                d[1] = pk_bf16(p2, p3);
                *(u32x2*)(sP + (h * 16 + l16) * SP_STRIDE + k4 * 16 + quad * 4) = d;
            }
        }
        asm volatile("" ::: "memory");
        bf16x8 pa[2][2];
#pragma unroll
        for (int h = 0; h < 2; h++)
#pragma unroll
            for (int kc = 0; kc < 2; kc++)
                pa[h][kc] = *(const bf16x8*)(sP + (h * 16 + l16) * SP_STRIDE + kc * 32 + quad * 8);
        asm volatile("" ::: "memory");

        // O += P V
#pragma unroll
        for (int kc = 0; kc < 2; kc++)
#pragma unroll
            for (int n = 0; n < 8; n++) {
                bf16x8 bv = *(const bf16x8*)(sV + (n * 16 + l16) * SV_STRIDE + kc * 32 + quad * 8);
                o[0][n] = __builtin_amdgcn_mfma_f32_16x16x32_bf16(pa[0][kc], bv, o[0][n], 0, 0, 0);
                o[1][n] = __builtin_amdgcn_mfma_f32_16x16x32_bf16(pa[1][kc], bv, o[1][n], 0, 0, 0);
            }
    }

    // row-sums reduce across quads; store lsum
#pragma unroll
    for (int h = 0; h < 2; h++) {
        rs[h] += __shfl_xor(rs[h], 16);
        rs[h] += __shfl_xor(rs[h], 32);
    }
    if (lane < 16) {
#pragma unroll
        for (int h = 0; h < 2; h++)
            lsum[(size_t)(split * 4 + b) * 4096 + qb * 128 + wave * 32 + h * 16 + lane] = rs[h];
    }

    // single-pass bf16 epilogue: sO [128 c][144] u16 = 36864 B (aliases all smem)
    __syncthreads();
    unsigned short* sO = smem;
    unsigned int* sO32 = (unsigned int*)smem;
#pragma unroll
    for (int h = 0; h < 2; h++)
#pragma unroll
        for (int n = 0; n < 8; n++) {
            int c = n * 16 + l16;
            int q = wave * 32 + h * 16 + quad * 4;     // even -> >>1 exact
            sO32[(c * 144 + q) >> 1] = pk_bf16(o[h][n][0], o[h][n][1]);
            sO32[(c * 144 + q + 2) >> 1] = pk_bf16(o[h][n][2], o[h][n][3]);
        }
    __syncthreads();
#pragma unroll
    for (int i = 0; i < 8; i++) {
        int u = i * 256 + t, c = u >> 4, chunk = u & 15;   // 128 c rows x 16 chunks of 16B
        *(uint4*)(opart + ((size_t)(split * 4 + b) * 128 + c) * 4096 + qb * 128 + chunk * 8) =
            *(const uint4*)(sO + c * 144 + chunk * 8);
    }
}

// ---------------- K3: combine splits + mask blend (bf16 opart) ---------------------------
__global__ void combine(const unsigned short* __restrict__ opart,
                        const float* __restrict__ lsum,
                        const float* __restrict__ x,
                        const float* __restrict__ mask,
                        float* __restrict__ out, int S) {
    const int qb = blockIdx.x, b = blockIdx.y, t = threadIdx.x;
    __shared__ float Linv[64];
    if (t < 64) {
        float L = 0.f;
        for (int s2 = 0; s2 < S; s2++)
            L += lsum[(size_t)(s2 * 4 + b) * 4096 + qb * 64 + t];
        Linv[t] = 1.f / fmaxf(L, 1e-37f);
    }
    __syncthreads();
#pragma unroll
    for (int i = 0; i < 8; i++) {
        int c = (t >> 4) + i * 16, qj = (t & 15) * 4;
        size_t qoff = (size_t)qb * 64 + qj;
        f32x4 acc = (f32x4){0.f, 0.f, 0.f, 0.f};
        for (int s2 = 0; s2 < S; s2++) {
            u16x4 pv = *(const u16x4*)(opart + ((size_t)(s2 * 4 + b) * 128 + c) * 4096 + qoff);
#pragma unroll
            for (int j = 0; j < 4; j++) acc[j] += bf2f(pv[j]);
        }
        f32x4 xv = *(const f32x4*)(x + ((size_t)b * 128 + c) * 4096 + qoff);
        f32x4 mv = *(const f32x4*)(mask + (size_t)b * 4096 + qoff);
        f32x4 res;
#pragma unroll
        for (int j = 0; j < 4; j++)
            res[j] = acc[j] * Linv[qj + j] * (1.f - mv[j]) * (1.f / 9.f) + xv[j] * mv[j];
        *(f32x4*)(out + ((size_t)b * 128 + c) * 4096 + qoff) = res;
    }
}

extern "C" void kernel_launch(void* const* d_in, const int* in_sizes, int n_in,
                              void* d_out, int out_size, void* d_ws, size_t ws_size,
                              hipStream_t stream) {
    const float* x = (const float*)d_in[0];     // f32 (4,128,64,64)
    const float* mask = (const float*)d_in[1];  // f32 (4,1,64,64)
    float* out = (float*)d_out;                 // f32 (4,128,64,64)
    char* ws = (char*)d_ws;
    unsigned short* kmat = (unsigned short*)(ws);
    unsigned short* kT   = (unsigned short*)(ws + (size_t)4 * 1024 * 1024);
    unsigned short* xbT  = (unsigned short*)(ws + (size_t)8 * 1024 * 1024);
    float* lsum          = (float*)(ws + (size_t)12 * 1024 * 1024);           // <= 512 KiB
    float* inv           = (float*)(ws + (size_t)12 * 1024 * 1024 + 512 * 1024);
    unsigned short* opart = (unsigned short*)(ws + (size_t)13 * 1024 * 1024); // S*4 MiB bf16

    // ws need: 13 MiB + S*4 MiB
    int S, qbshift;
    if (ws_size >= (size_t)45 * 1024 * 1024)      { S = 8; qbshift = 5; }
    else if (ws_size >= (size_t)29 * 1024 * 1024) { S = 4; qbshift = 4; }
    else if (ws_size >= (size_t)21 * 1024 * 1024) { S = 2; qbshift = 3; }
    else return;

    prep_inv<<<dim3(64, 4), 256, 0, stream>>>(x, inv);
    prep_main<<<dim3(64, 4, 2), 256, 0, stream>>>(x, inv, kmat, kT, xbT);
    flash_attn<<<dim3(32 * 4 * S), 256, 0, stream>>>(kmat, kT, xbT, opart, lsum, S, qbshift);
    combine<<<dim3(64, 4), 256, 0, stream>>>(opart, lsum, x, mask, out, S);
}

// Round 13
// 176.181 us; speedup vs baseline: 1.8110x; 1.4617x over previous
//
#include <hip/hip_runtime.h>

// CAttention on MI355X (gfx950). Inputs f32, output f32.
// Q = box3(x)*log2(e), K = V = normalize(x+EPS), softmax over keys, per batch.
// Round 13: kill the spill — K/V staging via __builtin_amdgcn_global_load_lds (width 16,
// no VGPR round-trip; R11/R12 spilled 64 staging VGPRs to scratch = 100s of MB).
// DMA needs lane-contiguous LDS rows -> sK/sV unpadded; bank conflicts removed by an
// XOR chunk swizzle applied in prep (kmat: g^=key&15, kT: h^=c&7) and mirrored in reads.
// LDS 34816 B, launch_bounds(256,3) -> 3 blocks/CU, 12 waves/CU.
// ws: kmat bf16 @0 | kT bf16 @4M | xbT bf16 @8M | lsum f32 @12M | inv f32 @12.5M | opart bf16 @13M.

typedef short bf16x8 __attribute__((ext_vector_type(8)));
typedef float f32x4 __attribute__((ext_vector_type(4)));
typedef unsigned short u16x4 __attribute__((ext_vector_type(4)));
typedef unsigned int u32x2 __attribute__((ext_vector_type(2)));

#define L2E 1.4426950408889634f

__device__ __forceinline__ unsigned short f2bf(float f) {
    unsigned int u;
    __builtin_memcpy(&u, &f, 4);
    u = u + 0x7FFFu + ((u >> 16) & 1u);   // RNE
    return (unsigned short)(u >> 16);
}
__device__ __forceinline__ float bf2f(unsigned short h) {
    unsigned int u = ((unsigned int)h) << 16;
    float f;
    __builtin_memcpy(&f, &u, 4);
    return f;
}
__device__ __forceinline__ unsigned int pk_bf16(float a, float b) {
    unsigned int ua, ub;
    __builtin_memcpy(&ua, &a, 4);
    __builtin_memcpy(&ub, &b, 4);
    return ((ua + 0x8000u) >> 16) | ((ub + 0x8000u) & 0xFFFF0000u);
}
// async global->LDS, 16B per lane; lptr must be wave-uniform (dst = lptr + lane*16)
__device__ __forceinline__ void gl_lds16(const unsigned short* g, unsigned short* l) {
    __builtin_amdgcn_global_load_lds(
        (const __attribute__((address_space(1))) unsigned int*)g,
        (__attribute__((address_space(3))) unsigned int*)l, 16, 0, 0);
}

// ---------------- K0: inv[b][l] = rsqrt(sum_c (x+eps)^2) ---------------------------------
__global__ void prep_inv(const float* __restrict__ x, float* __restrict__ inv) {
    const int b = blockIdx.y, l0 = blockIdx.x * 64, t = threadIdx.x;
    const int wave = t >> 6, lane = t & 63;
    const float* xb = x + (size_t)b * 128 * 4096 + l0 + lane;
    float sq = 0.f;
#pragma unroll
    for (int i = 0; i < 32; i++) {
        float v = xb[(size_t)(wave * 32 + i) * 4096] + 1e-7f;
        sq += v * v;
    }
    __shared__ float sqp[256];
    sqp[t] = sq;
    __syncthreads();
    if (t < 64)
        inv[b * 4096 + l0 + t] = rsqrtf(sqp[t] + sqp[64 + t] + sqp[128 + t] + sqp[192 + t]);
}

// ---------------- K1: prep_main: kmat (chunk-swizzled), kT (chunk-swizzled), xbT ---------
__global__ void prep_main(const float* __restrict__ x,
                          const float* __restrict__ inv,
                          unsigned short* __restrict__ kmat,
                          unsigned short* __restrict__ kT,
                          unsigned short* __restrict__ xbT) {
    const int p = blockIdx.x, b = blockIdx.y, cb = blockIdx.z * 64;
    const int t = threadIdx.x, wave = t >> 6, lane = t & 63;

    __shared__ float sX[8][3][66];
    __shared__ float sMidT[64 * 68];
    __shared__ __align__(16) unsigned short sQ[64 * 80];
    __shared__ float sInv[64];
    if (t < 64) sInv[t] = inv[b * 4096 + p * 64 + t];

    for (int c0 = 0; c0 < 64; c0 += 8) {
        __syncthreads();
#pragma unroll
        for (int i = 0; i < 6; i++) {
            int pair = wave * 6 + i;
            int cc = pair / 3, r = pair - cc * 3;
            int pp = p + r - 1;
            float v = 0.f;
            if ((unsigned)pp < 64u)
                v = x[((size_t)b * 128 + cb + c0 + cc) * 4096 + pp * 64 + lane];
            sX[cc][r][1 + lane] = v;
        }
        if (t < 48) {
            int cc = t / 6, rr = (t % 6) >> 1, side = t & 1;
            sX[cc][rr][side * 65] = 0.f;
        }
        __syncthreads();
#pragma unroll
        for (int j = 0; j < 2; j++) {
            int cc = wave * 2 + j;
            float mid = sX[cc][1][1 + lane] + 1e-7f;
            sMidT[lane * 68 + c0 + cc] = mid;
            float sbox = 0.f;
#pragma unroll
            for (int r = 0; r < 3; r++)
                sbox += sX[cc][r][lane] + sX[cc][r][lane + 1] + sX[cc][r][lane + 2];
            sQ[lane * 80 + c0 + cc] = f2bf(sbox * L2E);
        }
    }
    __syncthreads();

    // xbT rows: raw (flash reads Q frags straight from global)
#pragma unroll
    for (int i = 0; i < 2; i++) {
        int u = i * 256 + t, row = u >> 3, g = u & 7;
        *(bf16x8*)(xbT + ((size_t)b * 4096 + p * 64 + row) * 128 + cb + g * 8) =
            *(const bf16x8*)(sQ + row * 80 + g * 8);
    }
    // kmat rows, 16B chunk G stored at G ^ (key&15); key = p*64+q -> key&15 = q&15
#pragma unroll
    for (int i = 0; i < 2; i++) {
        int u = i * 256 + t, q = u >> 3, g = u & 7;
        float iv = sInv[q];
        f32x4 a = *(const f32x4*)(sMidT + q * 68 + g * 8);
        f32x4 c = *(const f32x4*)(sMidT + q * 68 + g * 8 + 4);
        unsigned int w[4];
        w[0] = pk_bf16(a[0] * iv, a[1] * iv);
        w[1] = pk_bf16(a[2] * iv, a[3] * iv);
        w[2] = pk_bf16(c[0] * iv, c[1] * iv);
        w[3] = pk_bf16(c[2] * iv, c[3] * iv);
        int Gs = ((int)blockIdx.z * 8 + g) ^ (q & 15);
        *(uint4*)(kmat + ((size_t)b * 4096 + p * 64 + q) * 128 + Gs * 8) =
            make_uint4(w[0], w[1], w[2], w[3]);
    }
    // kT rows: within each 64-aligned l-tile, 8-key chunk h stored at h ^ (c&7)
    {
        int cl = t >> 2, qg = t & 3;
        unsigned int w[8];
#pragma unroll
        for (int j = 0; j < 8; j++) {
            int ql = qg * 16 + j * 2;
            w[j] = pk_bf16(sMidT[ql * 68 + cl] * sInv[ql],
                           sMidT[(ql + 1) * 68 + cl] * sInv[ql + 1]);
        }
        unsigned short* dst = kT + ((size_t)b * 128 + cb + cl) * 4096 + p * 64;
        int h0 = (qg * 2) ^ (cl & 7), h1 = (qg * 2 + 1) ^ (cl & 7);
        *(uint4*)(dst + h0 * 8) = make_uint4(w[0], w[1], w[2], w[3]);
        *(uint4*)(dst + h1 * 8) = make_uint4(w[4], w[5], w[6], w[7]);
    }
}

// ---------------- K2: split-K flash, DMA staging, swizzled unpadded tiles ----------------
#define SP_STRIDE 72
#define SK_REGION 9216                  // sK raw 64*128=8192; sP (4*32*72=9216) aliases
#define SV_OFF 9216                     // sV raw 128*64=8192
#define SMEM_ELEMS (SK_REGION + 8192)   // 17408 u16 = 34816 B

__global__ void __launch_bounds__(256, 3) flash_attn(
        const unsigned short* __restrict__ kmat,
        const unsigned short* __restrict__ kT,
        const unsigned short* __restrict__ xbT,
        unsigned short* __restrict__ opart,
        float* __restrict__ lsum,
        int nsplit, int qbshift) {
    const int combo = blockIdx.x & (4 * nsplit - 1);
    const int qb = blockIdx.x >> qbshift;        // 128-query tile, 0..31
    const int b = combo & 3, split = combo >> 2;
    const int nk = 4096 / nsplit, NIT = nk >> 6, kt_base = split * nk;
    const int t = threadIdx.x;
    const int wave = t >> 6, lane = t & 63;
    const int l16 = lane & 15, quad = lane >> 4;

    __shared__ __align__(16) unsigned short smem[SMEM_ELEMS];
    unsigned short* sK = smem;                          // [64 keys][128], chunks swizzled
    unsigned short* sV = smem + SV_OFF;                 // [128 c][64], chunks swizzled
    unsigned short* sP = smem + wave * 32 * SP_STRIDE;  // aliases sK (dead after QK^T)

    // Q frags (B-operand of S^T): B[n=q=l16][k=c=quad*8+j]
    bf16x8 aq[2][4];
#pragma unroll
    for (int h = 0; h < 2; h++) {
        const unsigned short* xq =
            xbT + ((size_t)b * 4096 + qb * 128 + wave * 32 + h * 16 + l16) * 128 + quad * 8;
#pragma unroll
        for (int cc = 0; cc < 4; cc++) aq[h][cc] = *(const bf16x8*)(xq + cc * 32);
    }

    f32x4 o[2][8];
#pragma unroll
    for (int h = 0; h < 2; h++)
#pragma unroll
        for (int n = 0; n < 8; n++) o[h][n] = (f32x4){0.f, 0.f, 0.f, 0.f};
    float rs[2] = {0.f, 0.f};

    const unsigned short* kmb = kmat + (size_t)b * 4096 * 128;
    const unsigned short* ktb = kT + (size_t)b * 128 * 4096;

    for (int it = 0; it < NIT; it++) {
        const int kt0 = kt_base + it * 64;
        __syncthreads();                          // (A) prior iter's sP/sV reads done
        // async DMA staging: 16B/lane, LDS dst wave-uniform base + lane*16 (raw rows)
        {
            const unsigned short* gK = kmb + (size_t)kt0 * 128;
#pragma unroll
            for (int i = 0; i < 4; i++) {
                int e = i * 2048 + t * 8;
                gl_lds16(gK + e, sK + i * 2048 + wave * 512);
                gl_lds16(ktb + (size_t)(e >> 6) * 4096 + kt0 + (e & 63),
                         sV + i * 2048 + wave * 512);
            }
        }
        __syncthreads();                          // (B) vmcnt drained, tiles visible

        // S^T = K Q^T: lane holds S^T[key = k4*16 + quad*4 + r][q = l16]
        f32x4 s[2][4];
#pragma unroll
        for (int h = 0; h < 2; h++)
#pragma unroll
            for (int k4 = 0; k4 < 4; k4++) s[h][k4] = (f32x4){0.f, 0.f, 0.f, 0.f};
#pragma unroll
        for (int cc = 0; cc < 4; cc++) {
#pragma unroll
            for (int k4 = 0; k4 < 4; k4++) {
                // swizzled chunk read: key&15 == l16
                bf16x8 ak = *(const bf16x8*)(sK + (k4 * 16 + l16) * 128 +
                                             (((cc * 4 + quad) ^ l16) * 8));
                s[0][k4] = __builtin_amdgcn_mfma_f32_16x16x32_bf16(ak, aq[0][cc], s[0][k4], 0, 0, 0);
                s[1][k4] = __builtin_amdgcn_mfma_f32_16x16x32_bf16(ak, aq[1][cc], s[1][k4], 0, 0, 0);
            }
        }
        __syncthreads();                          // (C) QK reads done -> sP alias safe

        // p = 2^s; lane-local row-sum; b64-pack consecutive keys -> sP
#pragma unroll
        for (int h = 0; h < 2; h++) {
#pragma unroll
            for (int k4 = 0; k4 < 4; k4++) {
                float p0 = exp2f(s[h][k4][0]), p1 = exp2f(s[h][k4][1]);
                float p2 = exp2f(s[h][k4][2]), p3 = exp2f(s[h][k4][3]);
                rs[h] += (p0 + p1) + (p2 + p3);
                u32x2 d;
                d[0] = pk_bf16(p0, p1);
                d[1] = pk_bf16(p2, p3);
                *(u32x2*)(sP + (h * 16 + l16) * SP_STRIDE + k4 * 16 + quad * 4) = d;
            }
        }
        asm volatile("" ::: "memory");
        bf16x8 pa[2][2];
#pragma unroll
        for (int h = 0; h < 2; h++)
#pragma unroll
            for (int kc = 0; kc < 2; kc++)
                pa[h][kc] = *(const bf16x8*)(sP + (h * 16 + l16) * SP_STRIDE + kc * 32 + quad * 8);
        asm volatile("" ::: "memory");

        // O += P V : swizzled sV chunk read, c&7 == l16&7
#pragma unroll
        for (int kc = 0; kc < 2; kc++)
#pragma unroll
            for (int n = 0; n < 8; n++) {
                bf16x8 bv = *(const bf16x8*)(sV + (n * 16 + l16) * 64 +
                                             (((kc * 4 + quad) ^ (l16 & 7)) * 8));
                o[0][n] = __builtin_amdgcn_mfma_f32_16x16x32_bf16(pa[0][kc], bv, o[0][n], 0, 0, 0);
                o[1][n] = __builtin_amdgcn_mfma_f32_16x16x32_bf16(pa[1][kc], bv, o[1][n], 0, 0, 0);
            }
    }

    // row-sums reduce across quads; store lsum
#pragma unroll
    for (int h = 0; h < 2; h++) {
        rs[h] += __shfl_xor(rs[h], 16);
        rs[h] += __shfl_xor(rs[h], 32);
    }
    if (lane < 16) {
#pragma unroll
        for (int h = 0; h < 2; h++)
            lsum[(size_t)(split * 4 + b) * 4096 + qb * 128 + wave * 32 + h * 16 + lane] = rs[h];
    }

    // single-pass bf16 epilogue: sO [128 c][136] u16 = 17408 (aliases all smem)
    __syncthreads();
    unsigned short* sO = smem;
    unsigned int* sO32 = (unsigned int*)smem;
#pragma unroll
    for (int h = 0; h < 2; h++)
#pragma unroll
        for (int n = 0; n < 8; n++) {
            int c = n * 16 + l16;
            int q = wave * 32 + h * 16 + quad * 4;     // even -> >>1 exact
            sO32[(c * 136 + q) >> 1] = pk_bf16(o[h][n][0], o[h][n][1]);
            sO32[(c * 136 + q + 2) >> 1] = pk_bf16(o[h][n][2], o[h][n][3]);
        }
    __syncthreads();
#pragma unroll
    for (int i = 0; i < 8; i++) {
        int u = i * 256 + t, c = u >> 4, chunk = u & 15;   // 128 c rows x 16 chunks of 16B
        *(uint4*)(opart + ((size_t)(split * 4 + b) * 128 + c) * 4096 + qb * 128 + chunk * 8) =
            *(const uint4*)(sO + c * 136 + chunk * 8);
    }
}

// ---------------- K3: combine splits + mask blend (bf16 opart) ---------------------------
__global__ void combine(const unsigned short* __restrict__ opart,
                        const float* __restrict__ lsum,
                        const float* __restrict__ x,
                        const float* __restrict__ mask,
                        float* __restrict__ out, int S) {
    const int qb = blockIdx.x, b = blockIdx.y, t = threadIdx.x;
    __shared__ float Linv[64];
    if (t < 64) {
        float L = 0.f;
        for (int s2 = 0; s2 < S; s2++)
            L += lsum[(size_t)(s2 * 4 + b) * 4096 + qb * 64 + t];
        Linv[t] = 1.f / fmaxf(L, 1e-37f);
    }
    __syncthreads();
#pragma unroll
    for (int i = 0; i < 8; i++) {
        int c = (t >> 4) + i * 16, qj = (t & 15) * 4;
        size_t qoff = (size_t)qb * 64 + qj;
        f32x4 acc = (f32x4){0.f, 0.f, 0.f, 0.f};
        for (int s2 = 0; s2 < S; s2++) {
            u16x4 pv = *(const u16x4*)(opart + ((size_t)(s2 * 4 + b) * 128 + c) * 4096 + qoff);
#pragma unroll
            for (int j = 0; j < 4; j++) acc[j] += bf2f(pv[j]);
        }
        f32x4 xv = *(const f32x4*)(x + ((size_t)b * 128 + c) * 4096 + qoff);
        f32x4 mv = *(const f32x4*)(mask + (size_t)b * 4096 + qoff);
        f32x4 res;
#pragma unroll
        for (int j = 0; j < 4; j++)
            res[j] = acc[j] * Linv[qj + j] * (1.f - mv[j]) * (1.f / 9.f) + xv[j] * mv[j];
        *(f32x4*)(out + ((size_t)b * 128 + c) * 4096 + qoff) = res;
    }
}

extern "C" void kernel_launch(void* const* d_in, const int* in_sizes, int n_in,
                              void* d_out, int out_size, void* d_ws, size_t ws_size,
                              hipStream_t stream) {
    const float* x = (const float*)d_in[0];     // f32 (4,128,64,64)
    const float* mask = (const float*)d_in[1];  // f32 (4,1,64,64)
    float* out = (float*)d_out;                 // f32 (4,128,64,64)
    char* ws = (char*)d_ws;
    unsigned short* kmat = (unsigned short*)(ws);
    unsigned short* kT   = (unsigned short*)(ws + (size_t)4 * 1024 * 1024);
    unsigned short* xbT  = (unsigned short*)(ws + (size_t)8 * 1024 * 1024);
    float* lsum          = (float*)(ws + (size_t)12 * 1024 * 1024);
    float* inv           = (float*)(ws + (size_t)12 * 1024 * 1024 + 512 * 1024);
    unsigned short* opart = (unsigned short*)(ws + (size_t)13 * 1024 * 1024);

    // ws need: 13 MiB + S*4 MiB
    int S, qbshift;
    if (ws_size >= (size_t)45 * 1024 * 1024)      { S = 8; qbshift = 5; }
    else if (ws_size >= (size_t)29 * 1024 * 1024) { S = 4; qbshift = 4; }
    else if (ws_size >= (size_t)21 * 1024 * 1024) { S = 2; qbshift = 3; }
    else return;

    prep_inv<<<dim3(64, 4), 256, 0, stream>>>(x, inv);
    prep_main<<<dim3(64, 4, 2), 256, 0, stream>>>(x, inv, kmat, kT, xbT);
    flash_attn<<<dim3(32 * 4 * S), 256, 0, stream>>>(kmat, kT, xbT, opart, lsum, S, qbshift);
    combine<<<dim3(64, 4), 256, 0, stream>>>(opart, lsum, x, mask, out, S);
}

// Round 14
// 159.457 us; speedup vs baseline: 2.0010x; 1.1049x over previous
//
#include <hip/hip_runtime.h>

// CAttention on MI355X (gfx950). Inputs f32, output f32.
// Q = box3(x)*log2(e), K = V = normalize(x+EPS), softmax over keys, per batch.
// Round 14: double-buffered DMA flash — R13 drained vmcnt right after DMA issue (zero
// overlap, 75us). Now: bar1(drain prev-issued DMA) -> QK -> bar2 -> issue next DMA ->
// softmax+PV (hides it). LDS 2x34.8KB=69.6KB -> 2 blocks/CU @ (256,2), no spill possible.
// S=4 (LDS caps residency at 2 anyway; halves opart traffic). prep_inv fused into prep.
// ws: kmat bf16 @0 | kT bf16 @4M | xbT bf16 @8M | lsum f32 @12M | opart bf16 @13M.

typedef short bf16x8 __attribute__((ext_vector_type(8)));
typedef float f32x4 __attribute__((ext_vector_type(4)));
typedef unsigned short u16x4 __attribute__((ext_vector_type(4)));
typedef unsigned int u32x2 __attribute__((ext_vector_type(2)));

#define L2E 1.4426950408889634f

__device__ __forceinline__ unsigned short f2bf(float f) {
    unsigned int u;
    __builtin_memcpy(&u, &f, 4);
    u = u + 0x7FFFu + ((u >> 16) & 1u);   // RNE
    return (unsigned short)(u >> 16);
}
__device__ __forceinline__ float bf2f(unsigned short h) {
    unsigned int u = ((unsigned int)h) << 16;
    float f;
    __builtin_memcpy(&f, &u, 4);
    return f;
}
__device__ __forceinline__ unsigned int pk_bf16(float a, float b) {
    unsigned int ua, ub;
    __builtin_memcpy(&ua, &a, 4);
    __builtin_memcpy(&ub, &b, 4);
    return ((ua + 0x8000u) >> 16) | ((ub + 0x8000u) & 0xFFFF0000u);
}
// async global->LDS, 16B/lane; lptr wave-uniform (HW dst = lptr + lane*16)
__device__ __forceinline__ void gl_lds16(const unsigned short* g, unsigned short* l) {
    __builtin_amdgcn_global_load_lds(
        (const __attribute__((address_space(1))) unsigned int*)g,
        (__attribute__((address_space(3))) unsigned int*)l, 16, 0, 0);
}

// ---------------- K1: fused prep: inv (in-block) + kmat/kT (chunk-swizzled) + xbT --------
// grid (64 p, 4 b) x 256: block = one p-row (64 q), all 128 c.
__global__ void prep(const float* __restrict__ x,
                     unsigned short* __restrict__ kmat,
                     unsigned short* __restrict__ kT,
                     unsigned short* __restrict__ xbT) {
    const int p = blockIdx.x, b = blockIdx.y;
    const int t = threadIdx.x, wave = t >> 6, lane = t & 63;

    __shared__ float sX[8][3][66];
    __shared__ float sMidT[64 * 132];     // [q][c], f32, stride 132
    __shared__ __align__(16) unsigned short sQ[64 * 136];
    __shared__ float sqp[256];
    __shared__ float sInv[64];

    float sqacc = 0.f;
    for (int c0 = 0; c0 < 128; c0 += 8) {
        __syncthreads();
#pragma unroll
        for (int i = 0; i < 6; i++) {                 // 24 coalesced row loads
            int pair = wave * 6 + i;
            int cc = pair / 3, r = pair - cc * 3;
            int pp = p + r - 1;
            float v = 0.f;
            if ((unsigned)pp < 64u)
                v = x[((size_t)b * 128 + c0 + cc) * 4096 + pp * 64 + lane];
            sX[cc][r][1 + lane] = v;
        }
        if (t < 48) {                                 // zero q-borders
            int cc = t / 6, rr = (t % 6) >> 1, side = t & 1;
            sX[cc][rr][side * 65] = 0.f;
        }
        __syncthreads();
#pragma unroll
        for (int j = 0; j < 2; j++) {
            int cc = wave * 2 + j;
            float mid = sX[cc][1][1 + lane] + 1e-7f;
            sMidT[lane * 132 + c0 + cc] = mid;
            sqacc += mid * mid;
            float sbox = 0.f;
#pragma unroll
            for (int r = 0; r < 3; r++)
                sbox += sX[cc][r][lane] + sX[cc][r][lane + 1] + sX[cc][r][lane + 2];
            sQ[lane * 136 + c0 + cc] = f2bf(sbox * L2E);
        }
    }
    sqp[t] = sqacc;
    __syncthreads();
    if (t < 64)
        sInv[t] = rsqrtf(sqp[t] + sqp[64 + t] + sqp[128 + t] + sqp[192 + t]);
    __syncthreads();

    // xbT rows: raw
#pragma unroll
    for (int i = 0; i < 4; i++) {
        int u = i * 256 + t, row = u >> 4, g = u & 15;
        *(bf16x8*)(xbT + ((size_t)b * 4096 + p * 64 + row) * 128 + g * 8) =
            *(const bf16x8*)(sQ + row * 136 + g * 8);
    }
    // kmat rows: 16B chunk G stored at G ^ (q&15)  (key&15 == q&15)
#pragma unroll
    for (int i = 0; i < 4; i++) {
        int u = i * 256 + t, q = u >> 4, G = u & 15;
        float iv = sInv[q];
        f32x4 a = *(const f32x4*)(sMidT + q * 132 + G * 8);
        f32x4 c = *(const f32x4*)(sMidT + q * 132 + G * 8 + 4);
        unsigned int w[4];
        w[0] = pk_bf16(a[0] * iv, a[1] * iv);
        w[1] = pk_bf16(a[2] * iv, a[3] * iv);
        w[2] = pk_bf16(c[0] * iv, c[1] * iv);
        w[3] = pk_bf16(c[2] * iv, c[3] * iv);
        int Gs = G ^ (q & 15);
        *(uint4*)(kmat + ((size_t)b * 4096 + p * 64 + q) * 128 + Gs * 8) =
            make_uint4(w[0], w[1], w[2], w[3]);
    }
    // kT rows: within each 64-key tile, 8-key chunk h stored at h ^ (c&7)
#pragma unroll
    for (int i = 0; i < 2; i++) {
        int u = i * 256 + t, cl = u >> 2, qg = u & 3;
        unsigned int w[8];
#pragma unroll
        for (int j = 0; j < 8; j++) {
            int ql = qg * 16 + j * 2;
            w[j] = pk_bf16(sMidT[ql * 132 + cl] * sInv[ql],
                           sMidT[(ql + 1) * 132 + cl] * sInv[ql + 1]);
        }
        unsigned short* dst = kT + ((size_t)b * 128 + cl) * 4096 + p * 64;
        int h0 = (qg * 2) ^ (cl & 7), h1 = (qg * 2 + 1) ^ (cl & 7);
        *(uint4*)(dst + h0 * 8) = make_uint4(w[0], w[1], w[2], w[3]);
        *(uint4*)(dst + h1 * 8) = make_uint4(w[4], w[5], w[6], w[7]);
    }
}

// ---------------- K2: split-K flash, double-buffered DMA ---------------------------------
#define SP_STRIDE 72
#define BUF_STRIDE 17408               // sK region 9216 (raw 8192 + sP pad) + sV 8192
#define SMEM_ELEMS (2 * BUF_STRIDE)    // 34816 u16 = 69632 B -> 2 blocks/CU

__global__ void __launch_bounds__(256, 2) flash_attn(
        const unsigned short* __restrict__ kmat,
        const unsigned short* __restrict__ kT,
        const unsigned short* __restrict__ xbT,
        unsigned short* __restrict__ opart,
        float* __restrict__ lsum,
        int nsplit, int qbshift) {
    const int combo = blockIdx.x & (4 * nsplit - 1);
    const int qb = blockIdx.x >> qbshift;        // 128-query tile, 0..31
    const int b = combo & 3, split = combo >> 2;
    const int nk = 4096 / nsplit, NIT = nk >> 6, kt_base = split * nk;
    const int t = threadIdx.x;
    const int wave = t >> 6, lane = t & 63;
    const int l16 = lane & 15, quad = lane >> 4;

    __shared__ __align__(16) unsigned short smem[SMEM_ELEMS];

    // Q frags (B-operand of S^T): B[n=q=l16][k=c=quad*8+j]
    bf16x8 aq[2][4];
#pragma unroll
    for (int h = 0; h < 2; h++) {
        const unsigned short* xq =
            xbT + ((size_t)b * 4096 + qb * 128 + wave * 32 + h * 16 + l16) * 128 + quad * 8;
#pragma unroll
        for (int cc = 0; cc < 4; cc++) aq[h][cc] = *(const bf16x8*)(xq + cc * 32);
    }

    f32x4 o[2][8];
#pragma unroll
    for (int h = 0; h < 2; h++)
#pragma unroll
        for (int n = 0; n < 8; n++) o[h][n] = (f32x4){0.f, 0.f, 0.f, 0.f};
    float rs[2] = {0.f, 0.f};

    const unsigned short* kmb = kmat + (size_t)b * 4096 * 128;
    const unsigned short* ktb = kT + (size_t)b * 128 * 4096;

    // preload tile 0 into buffer 0
    {
        const unsigned short* gK = kmb + (size_t)kt_base * 128;
#pragma unroll
        for (int i = 0; i < 4; i++) {
            int e = i * 2048 + t * 8;
            gl_lds16(gK + e, smem + i * 2048 + wave * 512);
            gl_lds16(ktb + (size_t)(e >> 6) * 4096 + kt_base + (e & 63),
                     smem + 9216 + i * 2048 + wave * 512);
        }
    }

    for (int it = 0; it < NIT; it++) {
        const int base = (it & 1) * BUF_STRIDE;
        unsigned short* sK = smem + base;                 // [64 keys][128], swizzled chunks
        unsigned short* sV = smem + base + 9216;          // [128 c][64], swizzled chunks
        unsigned short* sP = sK + wave * 32 * SP_STRIDE;  // aliases sK (dead after QK^T)

        __syncthreads();   // bar1: drains this tile's DMA (issued one compute-phase ago)

        // S^T = K Q^T: lane holds S^T[key = k4*16 + quad*4 + r][q = l16]
        f32x4 s[2][4];
#pragma unroll
        for (int h = 0; h < 2; h++)
#pragma unroll
            for (int k4 = 0; k4 < 4; k4++) s[h][k4] = (f32x4){0.f, 0.f, 0.f, 0.f};
#pragma unroll
        for (int cc = 0; cc < 4; cc++) {
#pragma unroll
            for (int k4 = 0; k4 < 4; k4++) {
                bf16x8 ak = *(const bf16x8*)(sK + (k4 * 16 + l16) * 128 +
                                             (((cc * 4 + quad) ^ l16) * 8));
                s[0][k4] = __builtin_amdgcn_mfma_f32_16x16x32_bf16(ak, aq[0][cc], s[0][k4], 0, 0, 0);
                s[1][k4] = __builtin_amdgcn_mfma_f32_16x16x32_bf16(ak, aq[1][cc], s[1][k4], 0, 0, 0);
            }
        }
        __syncthreads();   // bar2: QK reads of sK done -> sP alias safe

        // issue next tile's DMA into the other buffer; hidden under softmax+PV
        if (it + 1 < NIT) {
            const int kt0 = kt_base + (it + 1) * 64;
            unsigned short* nb = smem + ((it + 1) & 1) * BUF_STRIDE;
            const unsigned short* gK = kmb + (size_t)kt0 * 128;
#pragma unroll
            for (int i = 0; i < 4; i++) {
                int e = i * 2048 + t * 8;
                gl_lds16(gK + e, nb + i * 2048 + wave * 512);
                gl_lds16(ktb + (size_t)(e >> 6) * 4096 + kt0 + (e & 63),
                         nb + 9216 + i * 2048 + wave * 512);
            }
        }

        // p = 2^s; lane-local row-sum; b64-pack consecutive keys -> sP
#pragma unroll
        for (int h = 0; h < 2; h++) {
#pragma unroll
            for (int k4 = 0; k4 < 4; k4++) {
                float p0 = exp2f(s[h][k4][0]), p1 = exp2f(s[h][k4][1]);
                float p2 = exp2f(s[h][k4][2]), p3 = exp2f(s[h][k4][3]);
                rs[h] += (p0 + p1) + (p2 + p3);
                u32x2 d;
                d[0] = pk_bf16(p0, p1);
                d[1] = pk_bf16(p2, p3);
                *(u32x2*)(sP + (h * 16 + l16) * SP_STRIDE + k4 * 16 + quad * 4) = d;
            }
        }
        asm volatile("" ::: "memory");
        bf16x8 pa[2][2];
#pragma unroll
        for (int h = 0; h < 2; h++)
#pragma unroll
            for (int kc = 0; kc < 2; kc++)
                pa[h][kc] = *(const bf16x8*)(sP + (h * 16 + l16) * SP_STRIDE + kc * 32 + quad * 8);
        asm volatile("" ::: "memory");

        // O += P V : swizzled sV chunk read (c&7 == l16&7)
#pragma unroll
        for (int kc = 0; kc < 2; kc++)
#pragma unroll
            for (int n = 0; n < 8; n++) {
                bf16x8 bv = *(const bf16x8*)(sV + (n * 16 + l16) * 64 +
                                             (((kc * 4 + quad) ^ (l16 & 7)) * 8));
                o[0][n] = __builtin_amdgcn_mfma_f32_16x16x32_bf16(pa[0][kc], bv, o[0][n], 0, 0, 0);
                o[1][n] = __builtin_amdgcn_mfma_f32_16x16x32_bf16(pa[1][kc], bv, o[1][n], 0, 0, 0);
            }
    }

    // row-sums reduce across quads; store lsum
#pragma unroll
    for (int h = 0; h < 2; h++) {
        rs[h] += __shfl_xor(rs[h], 16);
        rs[h] += __shfl_xor(rs[h], 32);
    }
    if (lane < 16) {
#pragma unroll
        for (int h = 0; h < 2; h++)
            lsum[(size_t)(split * 4 + b) * 4096 + qb * 128 + wave * 32 + h * 16 + lane] = rs[h];
    }

    // single-pass bf16 epilogue: sO [128 c][136] u16 = 17408 (aliases smem)
    __syncthreads();
    unsigned short* sO = smem;
    unsigned int* sO32 = (unsigned int*)smem;
#pragma unroll
    for (int h = 0; h < 2; h++)
#pragma unroll
        for (int n = 0; n < 8; n++) {
            int c = n * 16 + l16;
            int q = wave * 32 + h * 16 + quad * 4;     // even -> >>1 exact
            sO32[(c * 136 + q) >> 1] = pk_bf16(o[h][n][0], o[h][n][1]);
            sO32[(c * 136 + q + 2) >> 1] = pk_bf16(o[h][n][2], o[h][n][3]);
        }
    __syncthreads();
#pragma unroll
    for (int i = 0; i < 8; i++) {
        int u = i * 256 + t, c = u >> 4, chunk = u & 15;
        *(uint4*)(opart + ((size_t)(split * 4 + b) * 128 + c) * 4096 + qb * 128 + chunk * 8) =
            *(const uint4*)(sO + c * 136 + chunk * 8);
    }
}

// ---------------- K3: combine splits + mask blend (bf16 opart) ---------------------------
__global__ void combine(const unsigned short* __restrict__ opart,
                        const float* __restrict__ lsum,
                        const float* __restrict__ x,
                        const float* __restrict__ mask,
                        float* __restrict__ out, int S) {
    const int qb = blockIdx.x, b = blockIdx.y, t = threadIdx.x;
    __shared__ float Linv[64];
    if (t < 64) {
        float L = 0.f;
        for (int s2 = 0; s2 < S; s2++)
            L += lsum[(size_t)(s2 * 4 + b) * 4096 + qb * 64 + t];
        Linv[t] = 1.f / fmaxf(L, 1e-37f);
    }
    __syncthreads();
#pragma unroll
    for (int i = 0; i < 8; i++) {
        int c = (t >> 4) + i * 16, qj = (t & 15) * 4;
        size_t qoff = (size_t)qb * 64 + qj;
        f32x4 acc = (f32x4){0.f, 0.f, 0.f, 0.f};
        for (int s2 = 0; s2 < S; s2++) {
            u16x4 pv = *(const u16x4*)(opart + ((size_t)(s2 * 4 + b) * 128 + c) * 4096 + qoff);
#pragma unroll
            for (int j = 0; j < 4; j++) acc[j] += bf2f(pv[j]);
        }
        f32x4 xv = *(const f32x4*)(x + ((size_t)b * 128 + c) * 4096 + qoff);
        f32x4 mv = *(const f32x4*)(mask + (size_t)b * 4096 + qoff);
        f32x4 res;
#pragma unroll
        for (int j = 0; j < 4; j++)
            res[j] = acc[j] * Linv[qj + j] * (1.f - mv[j]) * (1.f / 9.f) + xv[j] * mv[j];
        *(f32x4*)(out + ((size_t)b * 128 + c) * 4096 + qoff) = res;
    }
}

extern "C" void kernel_launch(void* const* d_in, const int* in_sizes, int n_in,
                              void* d_out, int out_size, void* d_ws, size_t ws_size,
                              hipStream_t stream) {
    const float* x = (const float*)d_in[0];     // f32 (4,128,64,64)
    const float* mask = (const float*)d_in[1];  // f32 (4,1,64,64)
    float* out = (float*)d_out;                 // f32 (4,128,64,64)
    char* ws = (char*)d_ws;
    unsigned short* kmat = (unsigned short*)(ws);
    unsigned short* kT   = (unsigned short*)(ws + (size_t)4 * 1024 * 1024);
    unsigned short* xbT  = (unsigned short*)(ws + (size_t)8 * 1024 * 1024);
    float* lsum          = (float*)(ws + (size_t)12 * 1024 * 1024);
    unsigned short* opart = (unsigned short*)(ws + (size_t)13 * 1024 * 1024);

    // ws need: 13 MiB + S*4 MiB
    int S, qbshift;
    if (ws_size >= (size_t)29 * 1024 * 1024)      { S = 4; qbshift = 4; }
    else if (ws_size >= (size_t)21 * 1024 * 1024) { S = 2; qbshift = 3; }
    else return;

    prep<<<dim3(64, 4), 256, 0, stream>>>(x, kmat, kT, xbT);
    flash_attn<<<dim3(32 * 4 * S), 256, 0, stream>>>(kmat, kT, xbT, opart, lsum, S, qbshift);
    combine<<<dim3(64, 4), 256, 0, stream>>>(opart, lsum, x, mask, out, S);
}

// Round 15
// 143.738 us; speedup vs baseline: 2.2198x; 1.1094x over previous
//
#include <hip/hip_runtime.h>

// CAttention on MI355X (gfx950). Inputs f32, output f32.
// Q = box3(x)*log2(e), K = V = normalize(x+EPS), softmax over keys, per batch.
// Round 15: R14 (54us flash, verified) + raw v_exp_f32 via __builtin_amdgcn_exp2f
// (exp2f inlines OCML guard code ~5-6 instrs; 32 exps/iter = ~40% of VALUBusy 42%).
// Combine: 512 blocks (c-halves) + 16B opart loads. prep/flash otherwise identical.
// ws: kmat bf16 @0 | kT bf16 @4M | xbT bf16 @8M | lsum f32 @12M | opart bf16 @13M.

typedef short bf16x8 __attribute__((ext_vector_type(8)));
typedef float f32x4 __attribute__((ext_vector_type(4)));
typedef unsigned short u16x8 __attribute__((ext_vector_type(8)));
typedef unsigned int u32x2 __attribute__((ext_vector_type(2)));

#define L2E 1.4426950408889634f

__device__ __forceinline__ unsigned short f2bf(float f) {
    unsigned int u;
    __builtin_memcpy(&u, &f, 4);
    u = u + 0x7FFFu + ((u >> 16) & 1u);   // RNE
    return (unsigned short)(u >> 16);
}
__device__ __forceinline__ float bf2f(unsigned short h) {
    unsigned int u = ((unsigned int)h) << 16;
    float f;
    __builtin_memcpy(&f, &u, 4);
    return f;
}
__device__ __forceinline__ unsigned int pk_bf16(float a, float b) {
    unsigned int ua, ub;
    __builtin_memcpy(&ua, &a, 4);
    __builtin_memcpy(&ub, &b, 4);
    return ((ua + 0x8000u) >> 16) | ((ub + 0x8000u) & 0xFFFF0000u);
}
// async global->LDS, 16B/lane; lptr wave-uniform (HW dst = lptr + lane*16)
__device__ __forceinline__ void gl_lds16(const unsigned short* g, unsigned short* l) {
    __builtin_amdgcn_global_load_lds(
        (const __attribute__((address_space(1))) unsigned int*)g,
        (__attribute__((address_space(3))) unsigned int*)l, 16, 0, 0);
}

// ---------------- K1: fused prep: inv (in-block) + kmat/kT (chunk-swizzled) + xbT --------
// grid (64 p, 4 b) x 256: block = one p-row (64 q), all 128 c.
__global__ void prep(const float* __restrict__ x,
                     unsigned short* __restrict__ kmat,
                     unsigned short* __restrict__ kT,
                     unsigned short* __restrict__ xbT) {
    const int p = blockIdx.x, b = blockIdx.y;
    const int t = threadIdx.x, wave = t >> 6, lane = t & 63;

    __shared__ float sX[8][3][66];
    __shared__ float sMidT[64 * 132];     // [q][c], f32, stride 132
    __shared__ __align__(16) unsigned short sQ[64 * 136];
    __shared__ float sqp[256];
    __shared__ float sInv[64];

    float sqacc = 0.f;
    for (int c0 = 0; c0 < 128; c0 += 8) {
        __syncthreads();
#pragma unroll
        for (int i = 0; i < 6; i++) {                 // 24 coalesced row loads
            int pair = wave * 6 + i;
            int cc = pair / 3, r = pair - cc * 3;
            int pp = p + r - 1;
            float v = 0.f;
            if ((unsigned)pp < 64u)
                v = x[((size_t)b * 128 + c0 + cc) * 4096 + pp * 64 + lane];
            sX[cc][r][1 + lane] = v;
        }
        if (t < 48) {                                 // zero q-borders
            int cc = t / 6, rr = (t % 6) >> 1, side = t & 1;
            sX[cc][rr][side * 65] = 0.f;
        }
        __syncthreads();
#pragma unroll
        for (int j = 0; j < 2; j++) {
            int cc = wave * 2 + j;
            float mid = sX[cc][1][1 + lane] + 1e-7f;
            sMidT[lane * 132 + c0 + cc] = mid;
            sqacc += mid * mid;
            float sbox = 0.f;
#pragma unroll
            for (int r = 0; r < 3; r++)
                sbox += sX[cc][r][lane] + sX[cc][r][lane + 1] + sX[cc][r][lane + 2];
            sQ[lane * 136 + c0 + cc] = f2bf(sbox * L2E);
        }
    }
    sqp[t] = sqacc;
    __syncthreads();
    if (t < 64)
        sInv[t] = rsqrtf(sqp[t] + sqp[64 + t] + sqp[128 + t] + sqp[192 + t]);
    __syncthreads();

    // xbT rows: raw
#pragma unroll
    for (int i = 0; i < 4; i++) {
        int u = i * 256 + t, row = u >> 4, g = u & 15;
        *(bf16x8*)(xbT + ((size_t)b * 4096 + p * 64 + row) * 128 + g * 8) =
            *(const bf16x8*)(sQ + row * 136 + g * 8);
    }
    // kmat rows: 16B chunk G stored at G ^ (q&15)  (key&15 == q&15)
#pragma unroll
    for (int i = 0; i < 4; i++) {
        int u = i * 256 + t, q = u >> 4, G = u & 15;
        float iv = sInv[q];
        f32x4 a = *(const f32x4*)(sMidT + q * 132 + G * 8);
        f32x4 c = *(const f32x4*)(sMidT + q * 132 + G * 8 + 4);
        unsigned int w[4];
        w[0] = pk_bf16(a[0] * iv, a[1] * iv);
        w[1] = pk_bf16(a[2] * iv, a[3] * iv);
        w[2] = pk_bf16(c[0] * iv, c[1] * iv);
        w[3] = pk_bf16(c[2] * iv, c[3] * iv);
        int Gs = G ^ (q & 15);
        *(uint4*)(kmat + ((size_t)b * 4096 + p * 64 + q) * 128 + Gs * 8) =
            make_uint4(w[0], w[1], w[2], w[3]);
    }
    // kT rows: within each 64-key tile, 8-key chunk h stored at h ^ (c&7)
#pragma unroll
    for (int i = 0; i < 2; i++) {
        int u = i * 256 + t, cl = u >> 2, qg = u & 3;
        unsigned int w[8];
#pragma unroll
        for (int j = 0; j < 8; j++) {
            int ql = qg * 16 + j * 2;
            w[j] = pk_bf16(sMidT[ql * 132 + cl] * sInv[ql],
                           sMidT[(ql + 1) * 132 + cl] * sInv[ql + 1]);
        }
        unsigned short* dst = kT + ((size_t)b * 128 + cl) * 4096 + p * 64;
        int h0 = (qg * 2) ^ (cl & 7), h1 = (qg * 2 + 1) ^ (cl & 7);
        *(uint4*)(dst + h0 * 8) = make_uint4(w[0], w[1], w[2], w[3]);
        *(uint4*)(dst + h1 * 8) = make_uint4(w[4], w[5], w[6], w[7]);
    }
}

// ---------------- K2: split-K flash, double-buffered DMA ---------------------------------
#define SP_STRIDE 72
#define BUF_STRIDE 17408               // sK region 9216 (raw 8192 + sP pad) + sV 8192
#define SMEM_ELEMS (2 * BUF_STRIDE)    // 34816 u16 = 69632 B -> 2 blocks/CU

__global__ void __launch_bounds__(256, 2) flash_attn(
        const unsigned short* __restrict__ kmat,
        const unsigned short* __restrict__ kT,
        const unsigned short* __restrict__ xbT,
        unsigned short* __restrict__ opart,
        float* __restrict__ lsum,
        int nsplit, int qbshift) {
    const int combo = blockIdx.x & (4 * nsplit - 1);
    const int qb = blockIdx.x >> qbshift;        // 128-query tile, 0..31
    const int b = combo & 3, split = combo >> 2;
    const int nk = 4096 / nsplit, NIT = nk >> 6, kt_base = split * nk;
    const int t = threadIdx.x;
    const int wave = t >> 6, lane = t & 63;
    const int l16 = lane & 15, quad = lane >> 4;

    __shared__ __align__(16) unsigned short smem[SMEM_ELEMS];

    // Q frags (B-operand of S^T): B[n=q=l16][k=c=quad*8+j]
    bf16x8 aq[2][4];
#pragma unroll
    for (int h = 0; h < 2; h++) {
        const unsigned short* xq =
            xbT + ((size_t)b * 4096 + qb * 128 + wave * 32 + h * 16 + l16) * 128 + quad * 8;
#pragma unroll
        for (int cc = 0; cc < 4; cc++) aq[h][cc] = *(const bf16x8*)(xq + cc * 32);
    }

    f32x4 o[2][8];
#pragma unroll
    for (int h = 0; h < 2; h++)
#pragma unroll
        for (int n = 0; n < 8; n++) o[h][n] = (f32x4){0.f, 0.f, 0.f, 0.f};
    float rs[2] = {0.f, 0.f};

    const unsigned short* kmb = kmat + (size_t)b * 4096 * 128;
    const unsigned short* ktb = kT + (size_t)b * 128 * 4096;

    // preload tile 0 into buffer 0
    {
        const unsigned short* gK = kmb + (size_t)kt_base * 128;
#pragma unroll
        for (int i = 0; i < 4; i++) {
            int e = i * 2048 + t * 8;
            gl_lds16(gK + e, smem + i * 2048 + wave * 512);
            gl_lds16(ktb + (size_t)(e >> 6) * 4096 + kt_base + (e & 63),
                     smem + 9216 + i * 2048 + wave * 512);
        }
    }

    for (int it = 0; it < NIT; it++) {
        const int base = (it & 1) * BUF_STRIDE;
        unsigned short* sK = smem + base;                 // [64 keys][128], swizzled chunks
        unsigned short* sV = smem + base + 9216;          // [128 c][64], swizzled chunks
        unsigned short* sP = sK + wave * 32 * SP_STRIDE;  // aliases sK (dead after QK^T)

        __syncthreads();   // bar1: drains this tile's DMA (issued one compute-phase ago)

        // S^T = K Q^T: lane holds S^T[key = k4*16 + quad*4 + r][q = l16]
        f32x4 s[2][4];
#pragma unroll
        for (int h = 0; h < 2; h++)
#pragma unroll
            for (int k4 = 0; k4 < 4; k4++) s[h][k4] = (f32x4){0.f, 0.f, 0.f, 0.f};
#pragma unroll
        for (int cc = 0; cc < 4; cc++) {
#pragma unroll
            for (int k4 = 0; k4 < 4; k4++) {
                bf16x8 ak = *(const bf16x8*)(sK + (k4 * 16 + l16) * 128 +
                                             (((cc * 4 + quad) ^ l16) * 8));
                s[0][k4] = __builtin_amdgcn_mfma_f32_16x16x32_bf16(ak, aq[0][cc], s[0][k4], 0, 0, 0);
                s[1][k4] = __builtin_amdgcn_mfma_f32_16x16x32_bf16(ak, aq[1][cc], s[1][k4], 0, 0, 0);
            }
        }
        __syncthreads();   // bar2: QK reads of sK done -> sP alias safe

        // issue next tile's DMA into the other buffer; hidden under softmax+PV
        if (it + 1 < NIT) {
            const int kt0 = kt_base + (it + 1) * 64;
            unsigned short* nb = smem + ((it + 1) & 1) * BUF_STRIDE;
            const unsigned short* gK = kmb + (size_t)kt0 * 128;
#pragma unroll
            for (int i = 0; i < 4; i++) {
                int e = i * 2048 + t * 8;
                gl_lds16(gK + e, nb + i * 2048 + wave * 512);
                gl_lds16(ktb + (size_t)(e >> 6) * 4096 + kt0 + (e & 63),
                         nb + 9216 + i * 2048 + wave * 512);
            }
        }

        // p = 2^s via raw v_exp_f32; lane-local row-sum; b64-pack consecutive keys -> sP
#pragma unroll
        for (int h = 0; h < 2; h++) {
#pragma unroll
            for (int k4 = 0; k4 < 4; k4++) {
                float p0 = __builtin_amdgcn_exp2f(s[h][k4][0]);
                float p1 = __builtin_amdgcn_exp2f(s[h][k4][1]);
                float p2 = __builtin_amdgcn_exp2f(s[h][k4][2]);
                float p3 = __builtin_amdgcn_exp2f(s[h][k4][3]);
                rs[h] += (p0 + p1) + (p2 + p3);
                u32x2 d;
                d[0] = pk_bf16(p0, p1);
                d[1] = pk_bf16(p2, p3);
                *(u32x2*)(sP + (h * 16 + l16) * SP_STRIDE + k4 * 16 + quad * 4) = d;
            }
        }
        asm volatile("" ::: "memory");
        bf16x8 pa[2][2];
#pragma unroll
        for (int h = 0; h < 2; h++)
#pragma unroll
            for (int kc = 0; kc < 2; kc++)
                pa[h][kc] = *(const bf16x8*)(sP + (h * 16 + l16) * SP_STRIDE + kc * 32 + quad * 8);
        asm volatile("" ::: "memory");

        // O += P V : swizzled sV chunk read (c&7 == l16&7)
#pragma unroll
        for (int kc = 0; kc < 2; kc++)
#pragma unroll
            for (int n = 0; n < 8; n++) {
                bf16x8 bv = *(const bf16x8*)(sV + (n * 16 + l16) * 64 +
                                             (((kc * 4 + quad) ^ (l16 & 7)) * 8));
                o[0][n] = __builtin_amdgcn_mfma_f32_16x16x32_bf16(pa[0][kc], bv, o[0][n], 0, 0, 0);
                o[1][n] = __builtin_amdgcn_mfma_f32_16x16x32_bf16(pa[1][kc], bv, o[1][n], 0, 0, 0);
            }
    }

    // row-sums reduce across quads; store lsum
#pragma unroll
    for (int h = 0; h < 2; h++) {
        rs[h] += __shfl_xor(rs[h], 16);
        rs[h] += __shfl_xor(rs[h], 32);
    }
    if (lane < 16) {
#pragma unroll
        for (int h = 0; h < 2; h++)
            lsum[(size_t)(split * 4 + b) * 4096 + qb * 128 + wave * 32 + h * 16 + lane] = rs[h];
    }

    // single-pass bf16 epilogue: sO [128 c][136] u16 = 17408 (aliases smem)
    __syncthreads();
    unsigned short* sO = smem;
    unsigned int* sO32 = (unsigned int*)smem;
#pragma unroll
    for (int h = 0; h < 2; h++)
#pragma unroll
        for (int n = 0; n < 8; n++) {
            int c = n * 16 + l16;
            int q = wave * 32 + h * 16 + quad * 4;     // even -> >>1 exact
            sO32[(c * 136 + q) >> 1] = pk_bf16(o[h][n][0], o[h][n][1]);
            sO32[(c * 136 + q + 2) >> 1] = pk_bf16(o[h][n][2], o[h][n][3]);
        }
    __syncthreads();
#pragma unroll
    for (int i = 0; i < 8; i++) {
        int u = i * 256 + t, c = u >> 4, chunk = u & 15;
        *(uint4*)(opart + ((size_t)(split * 4 + b) * 128 + c) * 4096 + qb * 128 + chunk * 8) =
            *(const uint4*)(sO + c * 136 + chunk * 8);
    }
}

// ---------------- K3: combine splits + mask blend ----------------------------------------
// grid (64 qb64, 4 b, 2 cz) x 256: block = 64 q x 64 c.
__global__ void combine(const unsigned short* __restrict__ opart,
                        const float* __restrict__ lsum,
                        const float* __restrict__ x,
                        const float* __restrict__ mask,
                        float* __restrict__ out, int S) {
    const int qb = blockIdx.x, b = blockIdx.y, cz = blockIdx.z, t = threadIdx.x;
    __shared__ float Linv[64];
    if (t < 64) {
        float L = 0.f;
        for (int s2 = 0; s2 < S; s2++)
            L += lsum[(size_t)(s2 * 4 + b) * 4096 + qb * 64 + t];
        Linv[t] = 1.f / fmaxf(L, 1e-37f);
    }
    __syncthreads();
#pragma unroll
    for (int i = 0; i < 2; i++) {
        int u = i * 256 + t, c = cz * 64 + (u >> 3), qc = u & 7;
        size_t qoff = (size_t)qb * 64 + qc * 8;
        float acc[8] = {0.f, 0.f, 0.f, 0.f, 0.f, 0.f, 0.f, 0.f};
        for (int s2 = 0; s2 < S; s2++) {
            u16x8 pv = *(const u16x8*)(opart + ((size_t)(s2 * 4 + b) * 128 + c) * 4096 + qoff);
#pragma unroll
            for (int j = 0; j < 8; j++) acc[j] += bf2f(pv[j]);
        }
        const float* xr = x + ((size_t)b * 128 + c) * 4096 + qoff;
        const float* mr = mask + (size_t)b * 4096 + qoff;
        float* outr = out + ((size_t)b * 128 + c) * 4096 + qoff;
#pragma unroll
        for (int half = 0; half < 2; half++) {
            f32x4 xv = *(const f32x4*)(xr + half * 4);
            f32x4 mv = *(const f32x4*)(mr + half * 4);
            f32x4 res;
#pragma unroll
            for (int j = 0; j < 4; j++)
                res[j] = acc[half * 4 + j] * Linv[qc * 8 + half * 4 + j] *
                         (1.f - mv[j]) * (1.f / 9.f) + xv[j] * mv[j];
            *(f32x4*)(outr + half * 4) = res;
        }
    }
}

extern "C" void kernel_launch(void* const* d_in, const int* in_sizes, int n_in,
                              void* d_out, int out_size, void* d_ws, size_t ws_size,
                              hipStream_t stream) {
    const float* x = (const float*)d_in[0];     // f32 (4,128,64,64)
    const float* mask = (const float*)d_in[1];  // f32 (4,1,64,64)
    float* out = (float*)d_out;                 // f32 (4,128,64,64)
    char* ws = (char*)d_ws;
    unsigned short* kmat = (unsigned short*)(ws);
    unsigned short* kT   = (unsigned short*)(ws + (size_t)4 * 1024 * 1024);
    unsigned short* xbT  = (unsigned short*)(ws + (size_t)8 * 1024 * 1024);
    float* lsum          = (float*)(ws + (size_t)12 * 1024 * 1024);
    unsigned short* opart = (unsigned short*)(ws + (size_t)13 * 1024 * 1024);

    // ws need: 13 MiB + S*4 MiB
    int S, qbshift;
    if (ws_size >= (size_t)29 * 1024 * 1024)      { S = 4; qbshift = 4; }
    else if (ws_size >= (size_t)21 * 1024 * 1024) { S = 2; qbshift = 3; }
    else return;

    prep<<<dim3(64, 4), 256, 0, stream>>>(x, kmat, kT, xbT);
    flash_attn<<<dim3(32 * 4 * S), 256, 0, stream>>>(kmat, kT, xbT, opart, lsum, S, qbshift);
    combine<<<dim3(64, 4, 2), 256, 0, stream>>>(opart, lsum, x, mask, out, S);
}